// Round 5
// baseline (4137.902 us; speedup 1.0000x reference)
//
#include <hip/hip_runtime.h>
#include <hip/hip_bf16.h>

// Problem constants
#define S_TOT 5184      // total sequence
#define T_TXT 64        // text tokens
#define OFF0  64        // start of image0 (32x32)
#define OFF1  1088      // start of image1 (64x64)
#define NHEAD 16
#define CH    64        // channels per head
#define HID   1024
#define BATCH 4
#define BN_TOT (BATCH*NHEAD)   // 64
#define MTOT  (BATCH*S_TOT)    // 20736

typedef __attribute__((ext_vector_type(8))) short bf16x8;
typedef __attribute__((ext_vector_type(4))) float f32x4;

__device__ __forceinline__ unsigned int f2bf(float x) {
  unsigned int u = __float_as_uint(x);
  unsigned int r = u + 0x7fffu + ((u >> 16) & 1u);
  return r >> 16;   // RNE bf16 in low 16 bits
}
__device__ __forceinline__ float bflo(unsigned int u) { return __uint_as_float(u << 16); }
__device__ __forceinline__ float bfhi(unsigned int u) { return __uint_as_float(u & 0xffff0000u); }

__device__ __forceinline__ void gload_lds16(const short* g, short* l) {
  __builtin_amdgcn_global_load_lds(
      (const __attribute__((address_space(1))) unsigned int*)g,
      (__attribute__((address_space(3))) unsigned int*)l, 16, 0, 0);
}

// ---------------- conversion kernels ----------------
__global__ __launch_bounds__(256) void cvt_bf16(const float* __restrict__ in,
                                                unsigned int* __restrict__ out, int n8) {
  const int i = blockIdx.x * 256 + threadIdx.x;
  if (i >= n8) return;
  const float4 a = ((const float4*)in)[2 * i];
  const float4 b = ((const float4*)in)[2 * i + 1];
  uint4 r;
  r.x = f2bf(a.x) | (f2bf(a.y) << 16);
  r.y = f2bf(a.z) | (f2bf(a.w) << 16);
  r.z = f2bf(b.x) | (f2bf(b.y) << 16);
  r.w = f2bf(b.z) | (f2bf(b.w) << 16);
  ((uint4*)out)[i] = r;
}

// in: f32 [R][Cn] row-major -> out: bf16 [Cn][R]
__global__ void cvt_T(const float* __restrict__ in, short* __restrict__ out,
                      const int R, const int Cn) {
  __shared__ float t[32][33];
  const int bx = blockIdx.x * 32, by = blockIdx.y * 32;
  const int tx = threadIdx.x, ty = threadIdx.y;
#pragma unroll
  for (int ph = 0; ph < 4; ++ph)
    t[ty + ph * 8][tx] = in[(size_t)(by + ty + ph * 8) * Cn + bx + tx];
  __syncthreads();
#pragma unroll
  for (int ph = 0; ph < 4; ++ph)
    out[(size_t)(bx + ty + ph * 8) * R + by + tx] = (short)f2bf(t[tx][ty + ph * 8]);
}

// ---------------- bf16 MFMA GEMM: C = A(MxK) * BT(NxK)^T + bias ----------------
// EPI==0: f32 store to C.  EPI==1: scatter into q/k/v BF16 buffers [bh][s][64] (q * 0.125).
template<int EPI>
__global__ __launch_bounds__(256) void gemm_mfma(
    const short* __restrict__ A, const short* __restrict__ BT,
    const float* __restrict__ bias, float* __restrict__ C,
    unsigned short* __restrict__ qbuf, unsigned short* __restrict__ kbuf,
    unsigned short* __restrict__ vbuf,
    const int M, const int N, const int K)
{
  __shared__ short As[128 * 32];
  __shared__ short Bs[128 * 32];
  const int tid = threadIdx.x;
  const int w = tid >> 6, l = tid & 63;
  const int bm = blockIdx.x * 128, bn = blockIdx.y * 128;
  const int wr = w >> 1, wc = w & 1;
  const int lr = l & 15, lk = (l >> 4) * 8;

  const short* aSrc = A + (size_t)(bm + w * 32 + (l >> 2)) * K + (l & 3) * 8;
  const short* bSrc = BT + (size_t)(bn + w * 32 + (l >> 2)) * K + (l & 3) * 8;
  short* aDst = As + w * 32 * 32;
  short* bDst = Bs + w * 32 * 32;

  f32x4 acc[4][4];
#pragma unroll
  for (int m = 0; m < 4; ++m)
#pragma unroll
    for (int n = 0; n < 4; ++n) acc[m][n] = (f32x4){0.f, 0.f, 0.f, 0.f};

  for (int k0 = 0; k0 < K; k0 += 32) {
    gload_lds16(aSrc + k0,            aDst);
    gload_lds16(aSrc + k0 + 16 * K,   aDst + 16 * 32);
    gload_lds16(bSrc + k0,            bDst);
    gload_lds16(bSrc + k0 + 16 * K,   bDst + 16 * 32);
    __syncthreads();
    bf16x8 af[4], bfr[4];
#pragma unroll
    for (int m = 0; m < 4; ++m)
      af[m] = *(const bf16x8*)&As[(wr * 64 + m * 16 + lr) * 32 + lk];
#pragma unroll
    for (int n = 0; n < 4; ++n)
      bfr[n] = *(const bf16x8*)&Bs[(wc * 64 + n * 16 + lr) * 32 + lk];
#pragma unroll
    for (int m = 0; m < 4; ++m)
#pragma unroll
      for (int n = 0; n < 4; ++n)
        acc[m][n] = __builtin_amdgcn_mfma_f32_16x16x32_bf16(af[m], bfr[n], acc[m][n], 0, 0, 0);
    __syncthreads();
  }

#pragma unroll
  for (int m = 0; m < 4; ++m) {
    const int row0 = bm + wr * 64 + m * 16 + (l >> 4) * 4;
#pragma unroll
    for (int n = 0; n < 4; ++n) {
      const int col = bn + wc * 64 + n * 16 + lr;
      const float bv = bias[col];
      if constexpr (EPI == 0) {
#pragma unroll
        for (int i = 0; i < 4; ++i)
          C[(size_t)(row0 + i) * N + col] = acc[m][n][i] + bv;
      } else {
        const int type = col >> 10;            // 0=q 1=k 2=v
        const int head = (col & 1023) >> 6;
        const int chn  = col & 63;
        unsigned short* dst = (type == 0) ? qbuf : ((type == 1) ? kbuf : vbuf);
        const float sc = (type == 0) ? 0.125f : 1.f;
#pragma unroll
        for (int i = 0; i < 4; ++i) {
          const int row = row0 + i;
          const int b_ = row / S_TOT;
          const int s_ = row - b_ * S_TOT;
          dst[(((size_t)(b_ * NHEAD + head)) * S_TOT + s_) * CH + chn] =
              (unsigned short)f2bf((acc[m][n][i] + bv) * sc);
        }
      }
    }
  }
}

// ---------------- attention core helpers ----------------
// 2 lanes per query; each lane owns 32 channels (half*32 .. half*32+31), all bf16.

__device__ __forceinline__ float dot32bf(const float* __restrict__ q, const uint4* __restrict__ kp) {
  float s = 0.f;
#pragma unroll
  for (int i = 0; i < 4; ++i) {
    const uint4 u = kp[i];
    s = fmaf(bflo(u.x), q[8 * i + 0], s); s = fmaf(bfhi(u.x), q[8 * i + 1], s);
    s = fmaf(bflo(u.y), q[8 * i + 2], s); s = fmaf(bfhi(u.y), q[8 * i + 3], s);
    s = fmaf(bflo(u.z), q[8 * i + 4], s); s = fmaf(bfhi(u.z), q[8 * i + 5], s);
    s = fmaf(bflo(u.w), q[8 * i + 6], s); s = fmaf(bfhi(u.w), q[8 * i + 7], s);
  }
  return s;
}

// branch-free online-softmax update; invalid slots pass s = -1e30f (p -> 0)
__device__ __forceinline__ void onlineUpd(float s, const uint4* __restrict__ vp,
                                          float& m, float& l, float* __restrict__ acc) {
  const float d  = s - m;
  const float e  = __expf(-fabsf(d));
  const bool  g  = d > 0.f;
  const float sc = g ? e : 1.f;     // rescale of old state
  const float p  = g ? 1.f : e;     // weight of new term
  m = g ? s : m;
  l = fmaf(l, sc, p);
#pragma unroll
  for (int i = 0; i < 4; ++i) {
    const uint4 u = vp[i];
    acc[8 * i + 0] = fmaf(acc[8 * i + 0], sc, p * bflo(u.x));
    acc[8 * i + 1] = fmaf(acc[8 * i + 1], sc, p * bfhi(u.x));
    acc[8 * i + 2] = fmaf(acc[8 * i + 2], sc, p * bflo(u.y));
    acc[8 * i + 3] = fmaf(acc[8 * i + 3], sc, p * bfhi(u.y));
    acc[8 * i + 4] = fmaf(acc[8 * i + 4], sc, p * bflo(u.z));
    acc[8 * i + 5] = fmaf(acc[8 * i + 5], sc, p * bfhi(u.z));
    acc[8 * i + 6] = fmaf(acc[8 * i + 6], sc, p * bflo(u.w));
    acc[8 * i + 7] = fmaf(acc[8 * i + 7], sc, p * bfhi(u.w));
  }
}

__device__ __forceinline__ void load_q32(const unsigned short* __restrict__ qp, float* __restrict__ q) {
  const uint4* q4 = (const uint4*)qp;
#pragma unroll
  for (int i = 0; i < 4; ++i) {
    const uint4 u = q4[i];
    q[8 * i + 0] = bflo(u.x); q[8 * i + 1] = bfhi(u.x);
    q[8 * i + 2] = bflo(u.y); q[8 * i + 3] = bfhi(u.y);
    q[8 * i + 4] = bflo(u.z); q[8 * i + 5] = bfhi(u.z);
    q[8 * i + 6] = bflo(u.w); q[8 * i + 7] = bfhi(u.w);
  }
}

// text phase: 64 keys with additive mask, maskT is bf16 [64][MTOT]
__device__ __forceinline__ void text_phase(const float* __restrict__ q,
                                           const unsigned short* __restrict__ kt,
                                           const unsigned short* __restrict__ vt,
                                           const unsigned short* __restrict__ maskT,
                                           const int rowIdx,
                                           float& m, float& l, float* __restrict__ acc) {
#pragma unroll 2
  for (int j = 0; j < T_TXT; ++j) {
    float d = dot32bf(q, (const uint4*)(kt + j * CH));
    d += __shfl_xor(d, 1);
    const float mv = __uint_as_float(((unsigned int)maskT[(size_t)j * MTOT + rowIdx]) << 16);
    const float s = d * mv - 10000.f * (1.f - mv);
    onlineUpd(s, (const uint4*)(vt + j * CH), m, l, acc);
  }
}

// store all 32 owned channels (16 dwords) — round-4 bug was i<8 here
__device__ __forceinline__ void store_half_bf16(short* ctx, size_t base,
                                                const float* acc, float inv) {
  unsigned int* cp = (unsigned int*)(ctx + base);
#pragma unroll
  for (int i = 0; i < 16; ++i)
    cp[i] = f2bf(acc[2 * i] * inv) | (f2bf(acc[2 * i + 1] * inv) << 16);
}

// ---------------- attention: text queries ----------------
__global__ __launch_bounds__(256, 4) void attn_text(
    const unsigned short* __restrict__ qb, const unsigned short* __restrict__ kb,
    const unsigned short* __restrict__ vb, const unsigned short* __restrict__ maskT,
    short* __restrict__ ctx)
{
  const int t = blockIdx.x * 256 + threadIdx.x;
  const int half = t & 1;
  const int pair = t >> 1;
  const int bh = pair >> 6;
  const int tq = pair & 63;
  const int b_ = bh >> 4, head = bh & 15;

  float q[32];
  load_q32(qb + ((size_t)bh * S_TOT + tq) * CH + half * 32, q);

  float m = -1e30f, l = 0.f;
  float acc[32];
#pragma unroll
  for (int i = 0; i < 32; ++i) acc[i] = 0.f;

  const unsigned short* kt = kb + (size_t)bh * S_TOT * CH + half * 32;
  const unsigned short* vt = vb + (size_t)bh * S_TOT * CH + half * 32;
  text_phase(q, kt, vt, maskT, b_ * S_TOT + tq, m, l, acc);
  store_half_bf16(ctx, ((size_t)(b_ * S_TOT + tq)) * HID + head * CH + half * 32, acc, 1.f / l);
}

// ---------------- attention: image0 queries (32x32, 9x9 causal) ----------------
__global__ __launch_bounds__(256, 4) void attn_img0(
    const unsigned short* __restrict__ qb, const unsigned short* __restrict__ kb,
    const unsigned short* __restrict__ vb, const unsigned short* __restrict__ maskT,
    short* __restrict__ ctx)
{
  const int t = blockIdx.x * 256 + threadIdx.x;
  const int half = t & 1;
  const int pair = t >> 1;
  const int bh = pair >> 10;
  const int p = pair & 1023;
  const int qi = p >> 5, qj = p & 31;    // qi wave-uniform (32 pairs/wave)
  const int s = OFF0 + p;
  const int b_ = bh >> 4, head = bh & 15;

  float q[32];
  load_q32(qb + ((size_t)bh * S_TOT + s) * CH + half * 32, q);

  float m = -1e30f, l = 0.f;
  float acc[32];
#pragma unroll
  for (int i = 0; i < 32; ++i) acc[i] = 0.f;

  const unsigned short* kt = kb + (size_t)bh * S_TOT * CH + half * 32;
  const unsigned short* vt = vb + (size_t)bh * S_TOT * CH + half * 32;
  text_phase(q, kt, vt, maskT, b_ * S_TOT + s, m, l, acc);

  int cnt = 0;
  const unsigned short* k0 = kt + OFF0 * CH;
  const unsigned short* v0 = vt + OFF0 * CH;
  // rows di=-4..-1 (9 cols), row check wave-uniform
  for (int di = -4; di <= -1; ++di) {
    const int ki = qi + di;
    if (ki >= 0) {
#pragma unroll 2
      for (int jj = 0; jj < 9; ++jj) {
        const int kj = qj + jj - 4;
        const bool ok = (unsigned)kj < 32u;
        const int off = (ki * 32 + (ok ? kj : 0)) * CH;
        float d = dot32bf(q, (const uint4*)(k0 + off));
        d += __shfl_xor(d, 1);
        cnt += ok ? 0 : 1;
        onlineUpd(ok ? d : -1e30f, (const uint4*)(v0 + off), m, l, acc);
      }
    } else cnt += 9;
  }
  // row di=0, cols -4..0 (always in-grid row)
  {
#pragma unroll 2
    for (int jj = 0; jj < 5; ++jj) {
      const int kj = qj + jj - 4;
      const bool ok = (unsigned)kj < 32u;
      const int off = (qi * 32 + (ok ? kj : 0)) * CH;
      float d = dot32bf(q, (const uint4*)(k0 + off));
      d += __shfl_xor(d, 1);
      cnt += ok ? 0 : 1;
      onlineUpd(ok ? d : -1e30f, (const uint4*)(v0 + off), m, l, acc);
    }
  }
  l += (float)cnt * __expf(-m);   // OOB slots: score 0, value 0
  store_half_bf16(ctx, ((size_t)(b_ * S_TOT + s)) * HID + head * CH + half * 32, acc, 1.f / l);
}

// ---------------- attention: image1 queries (64x64; 7x7 over k0 + 9x9 causal over k1) ----------------
__global__ __launch_bounds__(256, 4) void attn_img1(
    const unsigned short* __restrict__ qb, const unsigned short* __restrict__ kb,
    const unsigned short* __restrict__ vb, const unsigned short* __restrict__ maskT,
    short* __restrict__ ctx)
{
  const int t = blockIdx.x * 256 + threadIdx.x;
  const int half = t & 1;
  const int pair = t >> 1;
  const int bh = pair >> 12;
  const int p = pair & 4095;
  const int qi = p >> 6, qj = p & 63;    // qi wave-uniform (32 pairs/wave)
  const int s = OFF1 + p;
  const int b_ = bh >> 4, head = bh & 15;

  float q[32];
  load_q32(qb + ((size_t)bh * S_TOT + s) * CH + half * 32, q);

  float m = -1e30f, l = 0.f;
  float acc[32];
#pragma unroll
  for (int i = 0; i < 32; ++i) acc[i] = 0.f;

  const unsigned short* kt = kb + (size_t)bh * S_TOT * CH + half * 32;
  const unsigned short* vt = vb + (size_t)bh * S_TOT * CH + half * 32;
  text_phase(q, kt, vt, maskT, b_ * S_TOT + s, m, l, acc);

  int cnt = 0;
  // 7x7 full window over k0 (32x32), base (qi/2, qj/2)
  {
    const unsigned short* k0 = kt + OFF0 * CH;
    const unsigned short* v0 = vt + OFF0 * CH;
    const int ki0 = qi >> 1, kj0 = qj >> 1;
    for (int di = -3; di <= 3; ++di) {
      const int ki = ki0 + di;
      if ((unsigned)ki < 32u) {
#pragma unroll 2
        for (int jj = 0; jj < 7; ++jj) {
          const int kj = kj0 + jj - 3;
          const bool ok = (unsigned)kj < 32u;
          const int off = (ki * 32 + (ok ? kj : 0)) * CH;
          float d = dot32bf(q, (const uint4*)(k0 + off));
          d += __shfl_xor(d, 1);
          cnt += ok ? 0 : 1;
          onlineUpd(ok ? d : -1e30f, (const uint4*)(v0 + off), m, l, acc);
        }
      } else cnt += 7;
    }
  }
  // 9x9 causal window over k1 (64x64)
  {
    const unsigned short* k1 = kt + OFF1 * CH;
    const unsigned short* v1 = vt + OFF1 * CH;
    for (int di = -4; di <= -1; ++di) {
      const int ki = qi + di;
      if (ki >= 0) {
#pragma unroll 2
        for (int jj = 0; jj < 9; ++jj) {
          const int kj = qj + jj - 4;
          const bool ok = (unsigned)kj < 64u;
          const int off = (ki * 64 + (ok ? kj : 0)) * CH;
          float d = dot32bf(q, (const uint4*)(k1 + off));
          d += __shfl_xor(d, 1);
          cnt += ok ? 0 : 1;
          onlineUpd(ok ? d : -1e30f, (const uint4*)(v1 + off), m, l, acc);
        }
      } else cnt += 9;
    }
    {
#pragma unroll 2
      for (int jj = 0; jj < 5; ++jj) {
        const int kj = qj + jj - 4;
        const bool ok = (unsigned)kj < 64u;
        const int off = (qi * 64 + (ok ? kj : 0)) * CH;
        float d = dot32bf(q, (const uint4*)(k1 + off));
        d += __shfl_xor(d, 1);
        cnt += ok ? 0 : 1;
        onlineUpd(ok ? d : -1e30f, (const uint4*)(v1 + off), m, l, acc);
      }
    }
  }
  l += (float)cnt * __expf(-m);   // OOB slots: score 0, value 0
  store_half_bf16(ctx, ((size_t)(b_ * S_TOT + s)) * HID + head * CH + half * 32, acc, 1.f / l);
}

// ---------------- launch ----------------
extern "C" void kernel_launch(void* const* d_in, const int* in_sizes, int n_in,
                              void* d_out, int out_size, void* d_ws, size_t ws_size,
                              hipStream_t stream) {
  const float* hidden = (const float*)d_in[0];
  const float* mask   = (const float*)d_in[1];
  const float* w_qkv  = (const float*)d_in[2];
  const float* b_qkv  = (const float*)d_in[3];
  const float* w_out  = (const float*)d_in[4];
  const float* b_out  = (const float*)d_in[5];
  float* out = (float*)d_out;

  const size_t NB = (size_t)BN_TOT * S_TOT * CH;   // 21,233,664 elements
  unsigned short* qbuf = (unsigned short*)d_ws;    // bf16
  unsigned short* kbuf = qbuf + NB;
  unsigned short* vbuf = kbuf + NB;
  short* hbf   = (short*)(vbuf + NB);              // hidden bf16; later ALIASED as ctx bf16
  short* wqkvT = hbf + NB;                         // [3072][1024] bf16
  short* woutT = wqkvT + (size_t)3072 * 1024;      // [1024][1024] bf16
  short* maskT = woutT + (size_t)1024 * 1024;      // [64][20736] bf16

  // 0) conversions
  cvt_bf16<<<(int)((NB / 8 + 255) / 256), 256, 0, stream>>>(hidden, (unsigned int*)hbf, (int)(NB / 8));
  cvt_T<<<dim3(3072 / 32, 1024 / 32), dim3(32, 8), 0, stream>>>(w_qkv, wqkvT, 1024, 3072);
  cvt_T<<<dim3(1024 / 32, 1024 / 32), dim3(32, 8), 0, stream>>>(w_out, woutT, 1024, 1024);
  cvt_T<<<dim3(T_TXT / 32, MTOT / 32), dim3(32, 8), 0, stream>>>(mask, maskT, MTOT, T_TXT);

  // 1) QKV projection (bf16 MFMA) with bf16 q/k/v scatter epilogue
  gemm_mfma<1><<<dim3(MTOT / 128, 3072 / 128), 256, 0, stream>>>(
      hbf, wqkvT, b_qkv, nullptr, qbuf, kbuf, vbuf, MTOT, 3072, 1024);

  // 2) attention (branch-free online softmax, 2 lanes/query, bf16 everywhere, f32 math)
  short* ctx = hbf;
  attn_text<<<(BN_TOT * T_TXT * 2) / 256, 256, 0, stream>>>(qbuf, kbuf, vbuf, (unsigned short*)maskT, ctx);
  attn_img0<<<(BN_TOT * 1024 * 2) / 256, 256, 0, stream>>>(qbuf, kbuf, vbuf, (unsigned short*)maskT, ctx);
  attn_img1<<<(BN_TOT * 4096 * 2) / 256, 256, 0, stream>>>(qbuf, kbuf, vbuf, (unsigned short*)maskT, ctx);

  // 3) output projection (bf16 MFMA)
  gemm_mfma<0><<<dim3(MTOT / 128, 1024 / 128), 256, 0, stream>>>(
      ctx, woutT, b_out, out, nullptr, nullptr, nullptr, MTOT, 1024, 1024);
}

// Round 6
// 1937.823 us; speedup vs baseline: 2.1353x; 2.1353x over previous
//
#include <hip/hip_runtime.h>
#include <hip/hip_bf16.h>

// Problem constants
#define S_TOT 5184      // total sequence
#define T_TXT 64        // text tokens
#define OFF0  64        // start of image0 (32x32)
#define OFF1  1088      // start of image1 (64x64)
#define NHEAD 16
#define CH    64        // channels per head
#define HID   1024
#define BATCH 4
#define BN_TOT (BATCH*NHEAD)   // 64
#define MTOT  (BATCH*S_TOT)    // 20736

typedef __attribute__((ext_vector_type(8))) short bf16x8;
typedef __attribute__((ext_vector_type(4))) float f32x4;

__device__ __forceinline__ unsigned int f2bf(float x) {
  unsigned int u = __float_as_uint(x);
  unsigned int r = u + 0x7fffu + ((u >> 16) & 1u);
  return r >> 16;   // RNE bf16 in low 16 bits
}
__device__ __forceinline__ float bflo(unsigned int u) { return __uint_as_float(u << 16); }
__device__ __forceinline__ float bfhi(unsigned int u) { return __uint_as_float(u & 0xffff0000u); }

__device__ __forceinline__ void gload_lds16(const short* g, short* l) {
  __builtin_amdgcn_global_load_lds(
      (const __attribute__((address_space(1))) unsigned int*)g,
      (__attribute__((address_space(3))) unsigned int*)l, 16, 0, 0);
}

// ---------------- conversion kernels ----------------
__global__ __launch_bounds__(256) void cvt_bf16(const float* __restrict__ in,
                                                unsigned int* __restrict__ out, int n8) {
  const int i = blockIdx.x * 256 + threadIdx.x;
  if (i >= n8) return;
  const float4 a = ((const float4*)in)[2 * i];
  const float4 b = ((const float4*)in)[2 * i + 1];
  uint4 r;
  r.x = f2bf(a.x) | (f2bf(a.y) << 16);
  r.y = f2bf(a.z) | (f2bf(a.w) << 16);
  r.z = f2bf(b.x) | (f2bf(b.y) << 16);
  r.w = f2bf(b.z) | (f2bf(b.w) << 16);
  ((uint4*)out)[i] = r;
}

// in: f32 [R][Cn] row-major -> out: bf16 [Cn][R]
__global__ void cvt_T(const float* __restrict__ in, short* __restrict__ out,
                      const int R, const int Cn) {
  __shared__ float t[32][33];
  const int bx = blockIdx.x * 32, by = blockIdx.y * 32;
  const int tx = threadIdx.x, ty = threadIdx.y;
#pragma unroll
  for (int ph = 0; ph < 4; ++ph)
    t[ty + ph * 8][tx] = in[(size_t)(by + ty + ph * 8) * Cn + bx + tx];
  __syncthreads();
#pragma unroll
  for (int ph = 0; ph < 4; ++ph)
    out[(size_t)(bx + ty + ph * 8) * R + by + tx] = (short)f2bf(t[tx][ty + ph * 8]);
}

// ---------------- bf16 MFMA GEMM: C = A(MxK) * BT(NxK)^T + bias ----------------
// EPI==0: f32 store to C.  EPI==1: scatter into q/k/v BF16 buffers [bh][s][64] (q * 0.125).
template<int EPI>
__global__ __launch_bounds__(256) void gemm_mfma(
    const short* __restrict__ A, const short* __restrict__ BT,
    const float* __restrict__ bias, float* __restrict__ C,
    unsigned short* __restrict__ qbuf, unsigned short* __restrict__ kbuf,
    unsigned short* __restrict__ vbuf,
    const int M, const int N, const int K)
{
  __shared__ short As[128 * 32];
  __shared__ short Bs[128 * 32];
  const int tid = threadIdx.x;
  const int w = tid >> 6, l = tid & 63;
  const int bm = blockIdx.x * 128, bn = blockIdx.y * 128;
  const int wr = w >> 1, wc = w & 1;
  const int lr = l & 15, lk = (l >> 4) * 8;

  const short* aSrc = A + (size_t)(bm + w * 32 + (l >> 2)) * K + (l & 3) * 8;
  const short* bSrc = BT + (size_t)(bn + w * 32 + (l >> 2)) * K + (l & 3) * 8;
  short* aDst = As + w * 32 * 32;
  short* bDst = Bs + w * 32 * 32;

  f32x4 acc[4][4];
#pragma unroll
  for (int m = 0; m < 4; ++m)
#pragma unroll
    for (int n = 0; n < 4; ++n) acc[m][n] = (f32x4){0.f, 0.f, 0.f, 0.f};

  for (int k0 = 0; k0 < K; k0 += 32) {
    gload_lds16(aSrc + k0,            aDst);
    gload_lds16(aSrc + k0 + 16 * K,   aDst + 16 * 32);
    gload_lds16(bSrc + k0,            bDst);
    gload_lds16(bSrc + k0 + 16 * K,   bDst + 16 * 32);
    __syncthreads();
    bf16x8 af[4], bfr[4];
#pragma unroll
    for (int m = 0; m < 4; ++m)
      af[m] = *(const bf16x8*)&As[(wr * 64 + m * 16 + lr) * 32 + lk];
#pragma unroll
    for (int n = 0; n < 4; ++n)
      bfr[n] = *(const bf16x8*)&Bs[(wc * 64 + n * 16 + lr) * 32 + lk];
#pragma unroll
    for (int m = 0; m < 4; ++m)
#pragma unroll
      for (int n = 0; n < 4; ++n)
        acc[m][n] = __builtin_amdgcn_mfma_f32_16x16x32_bf16(af[m], bfr[n], acc[m][n], 0, 0, 0);
    __syncthreads();
  }

#pragma unroll
  for (int m = 0; m < 4; ++m) {
    const int row0 = bm + wr * 64 + m * 16 + (l >> 4) * 4;
#pragma unroll
    for (int n = 0; n < 4; ++n) {
      const int col = bn + wc * 64 + n * 16 + lr;
      const float bv = bias[col];
      if constexpr (EPI == 0) {
#pragma unroll
        for (int i = 0; i < 4; ++i)
          C[(size_t)(row0 + i) * N + col] = acc[m][n][i] + bv;
      } else {
        const int type = col >> 10;            // 0=q 1=k 2=v
        const int head = (col & 1023) >> 6;
        const int chn  = col & 63;
        unsigned short* dst = (type == 0) ? qbuf : ((type == 1) ? kbuf : vbuf);
        const float sc = (type == 0) ? 0.125f : 1.f;
#pragma unroll
        for (int i = 0; i < 4; ++i) {
          const int row = row0 + i;
          const int b_ = row / S_TOT;
          const int s_ = row - b_ * S_TOT;
          dst[(((size_t)(b_ * NHEAD + head)) * S_TOT + s_) * CH + chn] =
              (unsigned short)f2bf((acc[m][n][i] + bv) * sc);
        }
      }
    }
  }
}

// ---------------- attention core helpers ----------------
// 4 lanes per query; each lane owns 16 channels (quar*16 .. quar*16+15), all bf16.

__device__ __forceinline__ float dot16bf(const float* __restrict__ q, const unsigned short* __restrict__ kp) {
  const uint4* k4 = (const uint4*)kp;
  const uint4 a = k4[0], b = k4[1];
  float s = 0.f;
  s = fmaf(bflo(a.x), q[0],  s); s = fmaf(bfhi(a.x), q[1],  s);
  s = fmaf(bflo(a.y), q[2],  s); s = fmaf(bfhi(a.y), q[3],  s);
  s = fmaf(bflo(a.z), q[4],  s); s = fmaf(bfhi(a.z), q[5],  s);
  s = fmaf(bflo(a.w), q[6],  s); s = fmaf(bfhi(a.w), q[7],  s);
  s = fmaf(bflo(b.x), q[8],  s); s = fmaf(bfhi(b.x), q[9],  s);
  s = fmaf(bflo(b.y), q[10], s); s = fmaf(bfhi(b.y), q[11], s);
  s = fmaf(bflo(b.z), q[12], s); s = fmaf(bfhi(b.z), q[13], s);
  s = fmaf(bflo(b.w), q[14], s); s = fmaf(bfhi(b.w), q[15], s);
  return s;
}

// branch-free online-softmax update; invalid slots pass s = -1e30f (p -> 0)
__device__ __forceinline__ void onlineUpd(float s, const unsigned short* __restrict__ vp,
                                          float& m, float& l, float* __restrict__ acc) {
  const float d  = s - m;
  const float e  = __expf(-fabsf(d));
  const bool  g  = d > 0.f;
  const float sc = g ? e : 1.f;     // rescale of old state
  const float p  = g ? 1.f : e;     // weight of new term
  m = g ? s : m;
  l = fmaf(l, sc, p);
  const uint4* v4 = (const uint4*)vp;
  const uint4 a = v4[0], b = v4[1];
  acc[0]  = fmaf(acc[0],  sc, p * bflo(a.x)); acc[1]  = fmaf(acc[1],  sc, p * bfhi(a.x));
  acc[2]  = fmaf(acc[2],  sc, p * bflo(a.y)); acc[3]  = fmaf(acc[3],  sc, p * bfhi(a.y));
  acc[4]  = fmaf(acc[4],  sc, p * bflo(a.z)); acc[5]  = fmaf(acc[5],  sc, p * bfhi(a.z));
  acc[6]  = fmaf(acc[6],  sc, p * bflo(a.w)); acc[7]  = fmaf(acc[7],  sc, p * bfhi(a.w));
  acc[8]  = fmaf(acc[8],  sc, p * bflo(b.x)); acc[9]  = fmaf(acc[9],  sc, p * bfhi(b.x));
  acc[10] = fmaf(acc[10], sc, p * bflo(b.y)); acc[11] = fmaf(acc[11], sc, p * bfhi(b.y));
  acc[12] = fmaf(acc[12], sc, p * bflo(b.z)); acc[13] = fmaf(acc[13], sc, p * bfhi(b.z));
  acc[14] = fmaf(acc[14], sc, p * bflo(b.w)); acc[15] = fmaf(acc[15], sc, p * bfhi(b.w));
}

__device__ __forceinline__ void load_q16(const unsigned short* __restrict__ qp, float* __restrict__ q) {
  const uint4* q4 = (const uint4*)qp;
  const uint4 a = q4[0], b = q4[1];
  q[0]  = bflo(a.x); q[1]  = bfhi(a.x); q[2]  = bflo(a.y); q[3]  = bfhi(a.y);
  q[4]  = bflo(a.z); q[5]  = bfhi(a.z); q[6]  = bflo(a.w); q[7]  = bfhi(a.w);
  q[8]  = bflo(b.x); q[9]  = bfhi(b.x); q[10] = bflo(b.y); q[11] = bfhi(b.y);
  q[12] = bflo(b.z); q[13] = bfhi(b.z); q[14] = bflo(b.w); q[15] = bfhi(b.w);
}

// text phase: 64 keys with additive mask, maskT is bf16 [64][MTOT]
__device__ __forceinline__ void text_phase(const float* __restrict__ q,
                                           const unsigned short* __restrict__ kt,
                                           const unsigned short* __restrict__ vt,
                                           const unsigned short* __restrict__ maskT,
                                           const int rowIdx,
                                           float& m, float& l, float* __restrict__ acc) {
#pragma unroll 2
  for (int j = 0; j < T_TXT; ++j) {
    float d = dot16bf(q, kt + j * CH);
    d += __shfl_xor(d, 1);
    d += __shfl_xor(d, 2);
    const float mv = __uint_as_float(((unsigned int)maskT[(size_t)j * MTOT + rowIdx]) << 16);
    const float s = d * mv - 10000.f * (1.f - mv);
    onlineUpd(s, vt + j * CH, m, l, acc);
  }
}

// store all 16 owned channels (8 dwords)
__device__ __forceinline__ void store_q16(short* ctx, size_t base,
                                          const float* acc, float inv) {
  unsigned int* cp = (unsigned int*)(ctx + base);
#pragma unroll
  for (int i = 0; i < 8; ++i)
    cp[i] = f2bf(acc[2 * i] * inv) | (f2bf(acc[2 * i + 1] * inv) << 16);
}

// ---------------- attention: text queries ----------------
__global__ __launch_bounds__(256, 4) void attn_text(
    const unsigned short* __restrict__ qb, const unsigned short* __restrict__ kb,
    const unsigned short* __restrict__ vb, const unsigned short* __restrict__ maskT,
    short* __restrict__ ctx)
{
  const int t = blockIdx.x * 256 + threadIdx.x;
  const int quar = t & 3;
  const int qidx = t >> 2;
  const int bh = qidx >> 6;
  const int tq = qidx & 63;
  const int b_ = bh >> 4, head = bh & 15;

  float q[16];
  load_q16(qb + ((size_t)bh * S_TOT + tq) * CH + quar * 16, q);

  float m = -1e30f, l = 0.f;
  float acc[16];
#pragma unroll
  for (int i = 0; i < 16; ++i) acc[i] = 0.f;

  const unsigned short* kt = kb + (size_t)bh * S_TOT * CH + quar * 16;
  const unsigned short* vt = vb + (size_t)bh * S_TOT * CH + quar * 16;
  text_phase(q, kt, vt, maskT, b_ * S_TOT + tq, m, l, acc);
  store_q16(ctx, ((size_t)(b_ * S_TOT + tq)) * HID + head * CH + quar * 16, acc, 1.f / l);
}

// ---------------- attention: image0 queries (32x32, 9x9 causal) ----------------
__global__ __launch_bounds__(256, 4) void attn_img0(
    const unsigned short* __restrict__ qb, const unsigned short* __restrict__ kb,
    const unsigned short* __restrict__ vb, const unsigned short* __restrict__ maskT,
    short* __restrict__ ctx)
{
  const int t = blockIdx.x * 256 + threadIdx.x;
  const int quar = t & 3;
  const int qidx = t >> 2;
  const int bh = qidx >> 10;
  const int p = qidx & 1023;
  const int qi = p >> 5, qj = p & 31;    // qi wave-uniform (16 queries/wave)
  const int s = OFF0 + p;
  const int b_ = bh >> 4, head = bh & 15;

  float q[16];
  load_q16(qb + ((size_t)bh * S_TOT + s) * CH + quar * 16, q);

  float m = -1e30f, l = 0.f;
  float acc[16];
#pragma unroll
  for (int i = 0; i < 16; ++i) acc[i] = 0.f;

  const unsigned short* kt = kb + (size_t)bh * S_TOT * CH + quar * 16;
  const unsigned short* vt = vb + (size_t)bh * S_TOT * CH + quar * 16;
  text_phase(q, kt, vt, maskT, b_ * S_TOT + s, m, l, acc);

  int cnt = 0;
  const unsigned short* k0 = kt + OFF0 * CH;
  const unsigned short* v0 = vt + OFF0 * CH;
  // rows di=-4..-1 (9 cols), row check wave-uniform
  for (int di = -4; di <= -1; ++di) {
    const int ki = qi + di;
    if (ki >= 0) {
#pragma unroll 2
      for (int jj = 0; jj < 9; ++jj) {
        const int kj = qj + jj - 4;
        const bool ok = (unsigned)kj < 32u;
        const int off = (ki * 32 + (ok ? kj : 0)) * CH;
        float d = dot16bf(q, k0 + off);
        d += __shfl_xor(d, 1);
        d += __shfl_xor(d, 2);
        cnt += ok ? 0 : 1;
        onlineUpd(ok ? d : -1e30f, v0 + off, m, l, acc);
      }
    } else cnt += 9;
  }
  // row di=0, cols -4..0 (always in-grid row)
  {
#pragma unroll 2
    for (int jj = 0; jj < 5; ++jj) {
      const int kj = qj + jj - 4;
      const bool ok = (unsigned)kj < 32u;
      const int off = (qi * 32 + (ok ? kj : 0)) * CH;
      float d = dot16bf(q, k0 + off);
      d += __shfl_xor(d, 1);
      d += __shfl_xor(d, 2);
      cnt += ok ? 0 : 1;
      onlineUpd(ok ? d : -1e30f, v0 + off, m, l, acc);
    }
  }
  l += (float)cnt * __expf(-m);   // OOB slots: score 0, value 0
  store_q16(ctx, ((size_t)(b_ * S_TOT + s)) * HID + head * CH + quar * 16, acc, 1.f / l);
}

// ---------------- attention: image1 queries (64x64; 7x7 over k0 + 9x9 causal over k1) ----------------
__global__ __launch_bounds__(256, 4) void attn_img1(
    const unsigned short* __restrict__ qb, const unsigned short* __restrict__ kb,
    const unsigned short* __restrict__ vb, const unsigned short* __restrict__ maskT,
    short* __restrict__ ctx)
{
  const int t = blockIdx.x * 256 + threadIdx.x;
  const int quar = t & 3;
  const int qidx = t >> 2;
  const int bh = qidx >> 12;
  const int p = qidx & 4095;
  const int qi = p >> 6, qj = p & 63;    // qi wave-uniform (16 queries/wave)
  const int s = OFF1 + p;
  const int b_ = bh >> 4, head = bh & 15;

  float q[16];
  load_q16(qb + ((size_t)bh * S_TOT + s) * CH + quar * 16, q);

  float m = -1e30f, l = 0.f;
  float acc[16];
#pragma unroll
  for (int i = 0; i < 16; ++i) acc[i] = 0.f;

  const unsigned short* kt = kb + (size_t)bh * S_TOT * CH + quar * 16;
  const unsigned short* vt = vb + (size_t)bh * S_TOT * CH + quar * 16;
  text_phase(q, kt, vt, maskT, b_ * S_TOT + s, m, l, acc);

  int cnt = 0;
  // 7x7 full window over k0 (32x32), base (qi/2, qj/2)
  {
    const unsigned short* k0 = kt + OFF0 * CH;
    const unsigned short* v0 = vt + OFF0 * CH;
    const int ki0 = qi >> 1, kj0 = qj >> 1;
    for (int di = -3; di <= 3; ++di) {
      const int ki = ki0 + di;
      if ((unsigned)ki < 32u) {
#pragma unroll 2
        for (int jj = 0; jj < 7; ++jj) {
          const int kj = kj0 + jj - 3;
          const bool ok = (unsigned)kj < 32u;
          const int off = (ki * 32 + (ok ? kj : 0)) * CH;
          float d = dot16bf(q, k0 + off);
          d += __shfl_xor(d, 1);
          d += __shfl_xor(d, 2);
          cnt += ok ? 0 : 1;
          onlineUpd(ok ? d : -1e30f, v0 + off, m, l, acc);
        }
      } else cnt += 7;
    }
  }
  // 9x9 causal window over k1 (64x64)
  {
    const unsigned short* k1 = kt + OFF1 * CH;
    const unsigned short* v1 = vt + OFF1 * CH;
    for (int di = -4; di <= -1; ++di) {
      const int ki = qi + di;
      if (ki >= 0) {
#pragma unroll 2
        for (int jj = 0; jj < 9; ++jj) {
          const int kj = qj + jj - 4;
          const bool ok = (unsigned)kj < 64u;
          const int off = (ki * 64 + (ok ? kj : 0)) * CH;
          float d = dot16bf(q, k1 + off);
          d += __shfl_xor(d, 1);
          d += __shfl_xor(d, 2);
          cnt += ok ? 0 : 1;
          onlineUpd(ok ? d : -1e30f, v1 + off, m, l, acc);
        }
      } else cnt += 9;
    }
    {
#pragma unroll 2
      for (int jj = 0; jj < 5; ++jj) {
        const int kj = qj + jj - 4;
        const bool ok = (unsigned)kj < 64u;
        const int off = (qi * 64 + (ok ? kj : 0)) * CH;
        float d = dot16bf(q, k1 + off);
        d += __shfl_xor(d, 1);
        d += __shfl_xor(d, 2);
        cnt += ok ? 0 : 1;
        onlineUpd(ok ? d : -1e30f, v1 + off, m, l, acc);
      }
    }
  }
  l += (float)cnt * __expf(-m);   // OOB slots: score 0, value 0
  store_q16(ctx, ((size_t)(b_ * S_TOT + s)) * HID + head * CH + quar * 16, acc, 1.f / l);
}

// ---------------- launch ----------------
extern "C" void kernel_launch(void* const* d_in, const int* in_sizes, int n_in,
                              void* d_out, int out_size, void* d_ws, size_t ws_size,
                              hipStream_t stream) {
  const float* hidden = (const float*)d_in[0];
  const float* mask   = (const float*)d_in[1];
  const float* w_qkv  = (const float*)d_in[2];
  const float* b_qkv  = (const float*)d_in[3];
  const float* w_out  = (const float*)d_in[4];
  const float* b_out  = (const float*)d_in[5];
  float* out = (float*)d_out;

  const size_t NB = (size_t)BN_TOT * S_TOT * CH;   // 21,233,664 elements
  unsigned short* qbuf = (unsigned short*)d_ws;    // bf16
  unsigned short* kbuf = qbuf + NB;
  unsigned short* vbuf = kbuf + NB;
  short* hbf   = (short*)(vbuf + NB);              // hidden bf16; later ALIASED as ctx bf16
  short* wqkvT = hbf + NB;                         // [3072][1024] bf16
  short* woutT = wqkvT + (size_t)3072 * 1024;      // [1024][1024] bf16
  short* maskT = woutT + (size_t)1024 * 1024;      // [64][20736] bf16

  // 0) conversions
  cvt_bf16<<<(int)((NB / 8 + 255) / 256), 256, 0, stream>>>(hidden, (unsigned int*)hbf, (int)(NB / 8));
  cvt_T<<<dim3(3072 / 32, 1024 / 32), dim3(32, 8), 0, stream>>>(w_qkv, wqkvT, 1024, 3072);
  cvt_T<<<dim3(1024 / 32, 1024 / 32), dim3(32, 8), 0, stream>>>(w_out, woutT, 1024, 1024);
  cvt_T<<<dim3(T_TXT / 32, MTOT / 32), dim3(32, 8), 0, stream>>>(mask, maskT, MTOT, T_TXT);

  // 1) QKV projection (bf16 MFMA) with bf16 q/k/v scatter epilogue
  gemm_mfma<1><<<dim3(MTOT / 128, 3072 / 128), 256, 0, stream>>>(
      hbf, wqkvT, b_qkv, nullptr, qbuf, kbuf, vbuf, MTOT, 3072, 1024);

  // 2) attention (branch-free online softmax, 4 lanes/query, bf16 everywhere, f32 math)
  short* ctx = hbf;
  attn_text<<<(BN_TOT * T_TXT * 4) / 256, 256, 0, stream>>>(qbuf, kbuf, vbuf, (unsigned short*)maskT, ctx);
  attn_img0<<<(BN_TOT * 1024 * 4) / 256, 256, 0, stream>>>(qbuf, kbuf, vbuf, (unsigned short*)maskT, ctx);
  attn_img1<<<(BN_TOT * 4096 * 4) / 256, 256, 0, stream>>>(qbuf, kbuf, vbuf, (unsigned short*)maskT, ctx);

  // 3) output projection (bf16 MFMA)
  gemm_mfma<0><<<dim3(MTOT / 128, 1024 / 128), 256, 0, stream>>>(
      ctx, woutT, b_out, out, nullptr, nullptr, nullptr, MTOT, 1024, 1024);
}

// Round 7
// 835.474 us; speedup vs baseline: 4.9528x; 2.3194x over previous
//
#include <hip/hip_runtime.h>
#include <hip/hip_bf16.h>

// Problem constants
#define S_TOT 5184      // total sequence
#define T_TXT 64        // text tokens
#define OFF0  64        // start of image0 (32x32)
#define OFF1  1088      // start of image1 (64x64)
#define NHEAD 16
#define CH    64        // channels per head
#define HID   1024
#define BATCH 4
#define BN_TOT (BATCH*NHEAD)   // 64
#define MTOT  (BATCH*S_TOT)    // 20736

typedef __attribute__((ext_vector_type(8))) short bf16x8;
typedef __attribute__((ext_vector_type(4))) float f32x4;

__device__ __forceinline__ unsigned int f2bf(float x) {
  unsigned int u = __float_as_uint(x);
  unsigned int r = u + 0x7fffu + ((u >> 16) & 1u);
  return r >> 16;   // RNE bf16 in low 16 bits
}
__device__ __forceinline__ float bflo(unsigned int u) { return __uint_as_float(u << 16); }
__device__ __forceinline__ float bfhi(unsigned int u) { return __uint_as_float(u & 0xffff0000u); }

__device__ __forceinline__ void gload_lds16(const short* g, short* l) {
  __builtin_amdgcn_global_load_lds(
      (const __attribute__((address_space(1))) unsigned int*)g,
      (__attribute__((address_space(3))) unsigned int*)l, 16, 0, 0);
}

// ---------------- conversion kernels ----------------
__global__ __launch_bounds__(256) void cvt_bf16(const float* __restrict__ in,
                                                unsigned int* __restrict__ out, int n8) {
  const int i = blockIdx.x * 256 + threadIdx.x;
  if (i >= n8) return;
  const float4 a = ((const float4*)in)[2 * i];
  const float4 b = ((const float4*)in)[2 * i + 1];
  uint4 r;
  r.x = f2bf(a.x) | (f2bf(a.y) << 16);
  r.y = f2bf(a.z) | (f2bf(a.w) << 16);
  r.z = f2bf(b.x) | (f2bf(b.y) << 16);
  r.w = f2bf(b.z) | (f2bf(b.w) << 16);
  ((uint4*)out)[i] = r;
}

// in: f32 [R][Cn] row-major -> out: bf16 [Cn][R]
__global__ void cvt_T(const float* __restrict__ in, short* __restrict__ out,
                      const int R, const int Cn) {
  __shared__ float t[32][33];
  const int bx = blockIdx.x * 32, by = blockIdx.y * 32;
  const int tx = threadIdx.x, ty = threadIdx.y;
#pragma unroll
  for (int ph = 0; ph < 4; ++ph)
    t[ty + ph * 8][tx] = in[(size_t)(by + ty + ph * 8) * Cn + bx + tx];
  __syncthreads();
#pragma unroll
  for (int ph = 0; ph < 4; ++ph)
    out[(size_t)(bx + ty + ph * 8) * R + by + tx] = (short)f2bf(t[tx][ty + ph * 8]);
}

// ---------------- bf16 MFMA GEMM: C = A(MxK) * BT(NxK)^T + bias ----------------
// EPI==0: f32 store to C.  EPI==1: scatter into q/k/v BF16 buffers [bh][s][64] (q * 0.125).
template<int EPI>
__global__ __launch_bounds__(256) void gemm_mfma(
    const short* __restrict__ A, const short* __restrict__ BT,
    const float* __restrict__ bias, float* __restrict__ C,
    unsigned short* __restrict__ qbuf, unsigned short* __restrict__ kbuf,
    unsigned short* __restrict__ vbuf,
    const int M, const int N, const int K)
{
  __shared__ short As[128 * 32];
  __shared__ short Bs[128 * 32];
  const int tid = threadIdx.x;
  const int w = tid >> 6, l = tid & 63;
  const int bm = blockIdx.x * 128, bn = blockIdx.y * 128;
  const int wr = w >> 1, wc = w & 1;
  const int lr = l & 15, lk = (l >> 4) * 8;

  const short* aSrc = A + (size_t)(bm + w * 32 + (l >> 2)) * K + (l & 3) * 8;
  const short* bSrc = BT + (size_t)(bn + w * 32 + (l >> 2)) * K + (l & 3) * 8;
  short* aDst = As + w * 32 * 32;
  short* bDst = Bs + w * 32 * 32;

  f32x4 acc[4][4];
#pragma unroll
  for (int m = 0; m < 4; ++m)
#pragma unroll
    for (int n = 0; n < 4; ++n) acc[m][n] = (f32x4){0.f, 0.f, 0.f, 0.f};

  for (int k0 = 0; k0 < K; k0 += 32) {
    gload_lds16(aSrc + k0,            aDst);
    gload_lds16(aSrc + k0 + 16 * K,   aDst + 16 * 32);
    gload_lds16(bSrc + k0,            bDst);
    gload_lds16(bSrc + k0 + 16 * K,   bDst + 16 * 32);
    __syncthreads();
    bf16x8 af[4], bfr[4];
#pragma unroll
    for (int m = 0; m < 4; ++m)
      af[m] = *(const bf16x8*)&As[(wr * 64 + m * 16 + lr) * 32 + lk];
#pragma unroll
    for (int n = 0; n < 4; ++n)
      bfr[n] = *(const bf16x8*)&Bs[(wc * 64 + n * 16 + lr) * 32 + lk];
#pragma unroll
    for (int m = 0; m < 4; ++m)
#pragma unroll
      for (int n = 0; n < 4; ++n)
        acc[m][n] = __builtin_amdgcn_mfma_f32_16x16x32_bf16(af[m], bfr[n], acc[m][n], 0, 0, 0);
    __syncthreads();
  }

#pragma unroll
  for (int m = 0; m < 4; ++m) {
    const int row0 = bm + wr * 64 + m * 16 + (l >> 4) * 4;
#pragma unroll
    for (int n = 0; n < 4; ++n) {
      const int col = bn + wc * 64 + n * 16 + lr;
      const float bv = bias[col];
      if constexpr (EPI == 0) {
#pragma unroll
        for (int i = 0; i < 4; ++i)
          C[(size_t)(row0 + i) * N + col] = acc[m][n][i] + bv;
      } else {
        const int type = col >> 10;            // 0=q 1=k 2=v
        const int head = (col & 1023) >> 6;
        const int chn  = col & 63;
        unsigned short* dst = (type == 0) ? qbuf : ((type == 1) ? kbuf : vbuf);
        const float sc = (type == 0) ? 0.125f : 1.f;
#pragma unroll
        for (int i = 0; i < 4; ++i) {
          const int row = row0 + i;
          const int b_ = row / S_TOT;
          const int s_ = row - b_ * S_TOT;
          dst[(((size_t)(b_ * NHEAD + head)) * S_TOT + s_) * CH + chn] =
              (unsigned short)f2bf((acc[m][n][i] + bv) * sc);
        }
      }
    }
  }
}

// ---------------- attention core helpers ----------------
// 4 lanes per query; each lane owns 16 channels (quar*16 .. quar*16+15), all bf16.

__device__ __forceinline__ float dot16bf(const float* __restrict__ q, const unsigned short* __restrict__ kp) {
  const uint4* k4 = (const uint4*)kp;
  const uint4 a = k4[0], b = k4[1];
  float s = 0.f;
  s = fmaf(bflo(a.x), q[0],  s); s = fmaf(bfhi(a.x), q[1],  s);
  s = fmaf(bflo(a.y), q[2],  s); s = fmaf(bfhi(a.y), q[3],  s);
  s = fmaf(bflo(a.z), q[4],  s); s = fmaf(bfhi(a.z), q[5],  s);
  s = fmaf(bflo(a.w), q[6],  s); s = fmaf(bfhi(a.w), q[7],  s);
  s = fmaf(bflo(b.x), q[8],  s); s = fmaf(bfhi(b.x), q[9],  s);
  s = fmaf(bflo(b.y), q[10], s); s = fmaf(bfhi(b.y), q[11], s);
  s = fmaf(bflo(b.z), q[12], s); s = fmaf(bfhi(b.z), q[13], s);
  s = fmaf(bflo(b.w), q[14], s); s = fmaf(bfhi(b.w), q[15], s);
  return s;
}

// branch-free online-softmax update; invalid slots pass s = -1e30f (p -> 0)
__device__ __forceinline__ void onlineUpd(float s, const unsigned short* __restrict__ vp,
                                          float& m, float& l, float* __restrict__ acc) {
  const float d  = s - m;
  const float e  = __expf(-fabsf(d));
  const bool  g  = d > 0.f;
  const float sc = g ? e : 1.f;     // rescale of old state
  const float p  = g ? 1.f : e;     // weight of new term
  m = g ? s : m;
  l = fmaf(l, sc, p);
  const uint4* v4 = (const uint4*)vp;
  const uint4 a = v4[0], b = v4[1];
  acc[0]  = fmaf(acc[0],  sc, p * bflo(a.x)); acc[1]  = fmaf(acc[1],  sc, p * bfhi(a.x));
  acc[2]  = fmaf(acc[2],  sc, p * bflo(a.y)); acc[3]  = fmaf(acc[3],  sc, p * bfhi(a.y));
  acc[4]  = fmaf(acc[4],  sc, p * bflo(a.z)); acc[5]  = fmaf(acc[5],  sc, p * bfhi(a.z));
  acc[6]  = fmaf(acc[6],  sc, p * bflo(a.w)); acc[7]  = fmaf(acc[7],  sc, p * bfhi(a.w));
  acc[8]  = fmaf(acc[8],  sc, p * bflo(b.x)); acc[9]  = fmaf(acc[9],  sc, p * bfhi(b.x));
  acc[10] = fmaf(acc[10], sc, p * bflo(b.y)); acc[11] = fmaf(acc[11], sc, p * bfhi(b.y));
  acc[12] = fmaf(acc[12], sc, p * bflo(b.z)); acc[13] = fmaf(acc[13], sc, p * bfhi(b.z));
  acc[14] = fmaf(acc[14], sc, p * bflo(b.w)); acc[15] = fmaf(acc[15], sc, p * bfhi(b.w));
}

__device__ __forceinline__ void load_q16(const unsigned short* __restrict__ qp, float* __restrict__ q) {
  const uint4* q4 = (const uint4*)qp;
  const uint4 a = q4[0], b = q4[1];
  q[0]  = bflo(a.x); q[1]  = bfhi(a.x); q[2]  = bflo(a.y); q[3]  = bfhi(a.y);
  q[4]  = bflo(a.z); q[5]  = bfhi(a.z); q[6]  = bflo(a.w); q[7]  = bfhi(a.w);
  q[8]  = bflo(b.x); q[9]  = bfhi(b.x); q[10] = bflo(b.y); q[11] = bfhi(b.y);
  q[12] = bflo(b.z); q[13] = bfhi(b.z); q[14] = bflo(b.w); q[15] = bfhi(b.w);
}

// text phase: 64 keys with additive mask, maskT is bf16 [64][MTOT]
__device__ __forceinline__ void text_phase(const float* __restrict__ q,
                                           const unsigned short* __restrict__ kt,
                                           const unsigned short* __restrict__ vt,
                                           const unsigned short* __restrict__ maskT,
                                           const int rowIdx,
                                           float& m, float& l, float* __restrict__ acc) {
#pragma unroll 2
  for (int j = 0; j < T_TXT; ++j) {
    float d = dot16bf(q, kt + j * CH);
    d += __shfl_xor(d, 1);
    d += __shfl_xor(d, 2);
    const float mv = __uint_as_float(((unsigned int)maskT[(size_t)j * MTOT + rowIdx]) << 16);
    const float s = d * mv - 10000.f * (1.f - mv);
    onlineUpd(s, vt + j * CH, m, l, acc);
  }
}

// store all 16 owned channels (8 dwords)
__device__ __forceinline__ void store_q16(short* ctx, size_t base,
                                          const float* acc, float inv) {
  unsigned int* cp = (unsigned int*)(ctx + base);
#pragma unroll
  for (int i = 0; i < 8; ++i)
    cp[i] = f2bf(acc[2 * i] * inv) | (f2bf(acc[2 * i + 1] * inv) << 16);
}

// ---------------- attention: text queries ----------------
// amdgpu_waves_per_eu(2,4): register budget 128-256, stops the allocator from
// chasing 8 waves/EU (64-VGPR target) and spilling the hot loop to scratch.
__global__ __launch_bounds__(256) __attribute__((amdgpu_waves_per_eu(2, 4)))
void attn_text(
    const unsigned short* __restrict__ qb, const unsigned short* __restrict__ kb,
    const unsigned short* __restrict__ vb, const unsigned short* __restrict__ maskT,
    short* __restrict__ ctx)
{
  const int t = blockIdx.x * 256 + threadIdx.x;
  const int quar = t & 3;
  const int qidx = t >> 2;
  const int bh = qidx >> 6;
  const int tq = qidx & 63;
  const int b_ = bh >> 4, head = bh & 15;

  float q[16];
  load_q16(qb + ((size_t)bh * S_TOT + tq) * CH + quar * 16, q);

  float m = -1e30f, l = 0.f;
  float acc[16];
#pragma unroll
  for (int i = 0; i < 16; ++i) acc[i] = 0.f;

  const unsigned short* kt = kb + (size_t)bh * S_TOT * CH + quar * 16;
  const unsigned short* vt = vb + (size_t)bh * S_TOT * CH + quar * 16;
  text_phase(q, kt, vt, maskT, b_ * S_TOT + tq, m, l, acc);
  store_q16(ctx, ((size_t)(b_ * S_TOT + tq)) * HID + head * CH + quar * 16, acc, 1.f / l);
}

// ---------------- attention: image0 queries (32x32, 9x9 causal) ----------------
__global__ __launch_bounds__(256) __attribute__((amdgpu_waves_per_eu(2, 4)))
void attn_img0(
    const unsigned short* __restrict__ qb, const unsigned short* __restrict__ kb,
    const unsigned short* __restrict__ vb, const unsigned short* __restrict__ maskT,
    short* __restrict__ ctx)
{
  const int t = blockIdx.x * 256 + threadIdx.x;
  const int quar = t & 3;
  const int qidx = t >> 2;
  const int bh = qidx >> 10;
  const int p = qidx & 1023;
  const int qi = p >> 5, qj = p & 31;    // qi wave-uniform (16 queries/wave)
  const int s = OFF0 + p;
  const int b_ = bh >> 4, head = bh & 15;

  float q[16];
  load_q16(qb + ((size_t)bh * S_TOT + s) * CH + quar * 16, q);

  float m = -1e30f, l = 0.f;
  float acc[16];
#pragma unroll
  for (int i = 0; i < 16; ++i) acc[i] = 0.f;

  const unsigned short* kt = kb + (size_t)bh * S_TOT * CH + quar * 16;
  const unsigned short* vt = vb + (size_t)bh * S_TOT * CH + quar * 16;
  text_phase(q, kt, vt, maskT, b_ * S_TOT + s, m, l, acc);

  int cnt = 0;
  const unsigned short* k0 = kt + OFF0 * CH;
  const unsigned short* v0 = vt + OFF0 * CH;
  // rows di=-4..-1 (9 cols), row check wave-uniform
  for (int di = -4; di <= -1; ++di) {
    const int ki = qi + di;
    if (ki >= 0) {
#pragma unroll 2
      for (int jj = 0; jj < 9; ++jj) {
        const int kj = qj + jj - 4;
        const bool ok = (unsigned)kj < 32u;
        const int off = (ki * 32 + (ok ? kj : 0)) * CH;
        float d = dot16bf(q, k0 + off);
        d += __shfl_xor(d, 1);
        d += __shfl_xor(d, 2);
        cnt += ok ? 0 : 1;
        onlineUpd(ok ? d : -1e30f, v0 + off, m, l, acc);
      }
    } else cnt += 9;
  }
  // row di=0, cols -4..0 (always in-grid row)
  {
#pragma unroll 2
    for (int jj = 0; jj < 5; ++jj) {
      const int kj = qj + jj - 4;
      const bool ok = (unsigned)kj < 32u;
      const int off = (qi * 32 + (ok ? kj : 0)) * CH;
      float d = dot16bf(q, k0 + off);
      d += __shfl_xor(d, 1);
      d += __shfl_xor(d, 2);
      cnt += ok ? 0 : 1;
      onlineUpd(ok ? d : -1e30f, v0 + off, m, l, acc);
    }
  }
  l += (float)cnt * __expf(-m);   // OOB slots: score 0, value 0
  store_q16(ctx, ((size_t)(b_ * S_TOT + s)) * HID + head * CH + quar * 16, acc, 1.f / l);
}

// ---------------- attention: image1 queries (64x64; 7x7 over k0 + 9x9 causal over k1) ----------------
__global__ __launch_bounds__(256) __attribute__((amdgpu_waves_per_eu(2, 4)))
void attn_img1(
    const unsigned short* __restrict__ qb, const unsigned short* __restrict__ kb,
    const unsigned short* __restrict__ vb, const unsigned short* __restrict__ maskT,
    short* __restrict__ ctx)
{
  const int t = blockIdx.x * 256 + threadIdx.x;
  const int quar = t & 3;
  const int qidx = t >> 2;
  const int bh = qidx >> 12;
  const int p = qidx & 4095;
  const int qi = p >> 6, qj = p & 63;    // qi wave-uniform (16 queries/wave)
  const int s = OFF1 + p;
  const int b_ = bh >> 4, head = bh & 15;

  float q[16];
  load_q16(qb + ((size_t)bh * S_TOT + s) * CH + quar * 16, q);

  float m = -1e30f, l = 0.f;
  float acc[16];
#pragma unroll
  for (int i = 0; i < 16; ++i) acc[i] = 0.f;

  const unsigned short* kt = kb + (size_t)bh * S_TOT * CH + quar * 16;
  const unsigned short* vt = vb + (size_t)bh * S_TOT * CH + quar * 16;
  text_phase(q, kt, vt, maskT, b_ * S_TOT + s, m, l, acc);

  int cnt = 0;
  // 7x7 full window over k0 (32x32), base (qi/2, qj/2)
  {
    const unsigned short* k0 = kt + OFF0 * CH;
    const unsigned short* v0 = vt + OFF0 * CH;
    const int ki0 = qi >> 1, kj0 = qj >> 1;
    for (int di = -3; di <= 3; ++di) {
      const int ki = ki0 + di;
      if ((unsigned)ki < 32u) {
#pragma unroll 2
        for (int jj = 0; jj < 7; ++jj) {
          const int kj = kj0 + jj - 3;
          const bool ok = (unsigned)kj < 32u;
          const int off = (ki * 32 + (ok ? kj : 0)) * CH;
          float d = dot16bf(q, k0 + off);
          d += __shfl_xor(d, 1);
          d += __shfl_xor(d, 2);
          cnt += ok ? 0 : 1;
          onlineUpd(ok ? d : -1e30f, v0 + off, m, l, acc);
        }
      } else cnt += 7;
    }
  }
  // 9x9 causal window over k1 (64x64)
  {
    const unsigned short* k1 = kt + OFF1 * CH;
    const unsigned short* v1 = vt + OFF1 * CH;
    for (int di = -4; di <= -1; ++di) {
      const int ki = qi + di;
      if (ki >= 0) {
#pragma unroll 2
        for (int jj = 0; jj < 9; ++jj) {
          const int kj = qj + jj - 4;
          const bool ok = (unsigned)kj < 64u;
          const int off = (ki * 64 + (ok ? kj : 0)) * CH;
          float d = dot16bf(q, k1 + off);
          d += __shfl_xor(d, 1);
          d += __shfl_xor(d, 2);
          cnt += ok ? 0 : 1;
          onlineUpd(ok ? d : -1e30f, v1 + off, m, l, acc);
        }
      } else cnt += 9;
    }
    {
#pragma unroll 2
      for (int jj = 0; jj < 5; ++jj) {
        const int kj = qj + jj - 4;
        const bool ok = (unsigned)kj < 64u;
        const int off = (qi * 64 + (ok ? kj : 0)) * CH;
        float d = dot16bf(q, k1 + off);
        d += __shfl_xor(d, 1);
        d += __shfl_xor(d, 2);
        cnt += ok ? 0 : 1;
        onlineUpd(ok ? d : -1e30f, v1 + off, m, l, acc);
      }
    }
  }
  l += (float)cnt * __expf(-m);   // OOB slots: score 0, value 0
  store_q16(ctx, ((size_t)(b_ * S_TOT + s)) * HID + head * CH + quar * 16, acc, 1.f / l);
}

// ---------------- launch ----------------
extern "C" void kernel_launch(void* const* d_in, const int* in_sizes, int n_in,
                              void* d_out, int out_size, void* d_ws, size_t ws_size,
                              hipStream_t stream) {
  const float* hidden = (const float*)d_in[0];
  const float* mask   = (const float*)d_in[1];
  const float* w_qkv  = (const float*)d_in[2];
  const float* b_qkv  = (const float*)d_in[3];
  const float* w_out  = (const float*)d_in[4];
  const float* b_out  = (const float*)d_in[5];
  float* out = (float*)d_out;

  const size_t NB = (size_t)BN_TOT * S_TOT * CH;   // 21,233,664 elements
  unsigned short* qbuf = (unsigned short*)d_ws;    // bf16
  unsigned short* kbuf = qbuf + NB;
  unsigned short* vbuf = kbuf + NB;
  short* hbf   = (short*)(vbuf + NB);              // hidden bf16; later ALIASED as ctx bf16
  short* wqkvT = hbf + NB;                         // [3072][1024] bf16
  short* woutT = wqkvT + (size_t)3072 * 1024;      // [1024][1024] bf16
  short* maskT = woutT + (size_t)1024 * 1024;      // [64][20736] bf16

  // 0) conversions
  cvt_bf16<<<(int)((NB / 8 + 255) / 256), 256, 0, stream>>>(hidden, (unsigned int*)hbf, (int)(NB / 8));
  cvt_T<<<dim3(3072 / 32, 1024 / 32), dim3(32, 8), 0, stream>>>(w_qkv, wqkvT, 1024, 3072);
  cvt_T<<<dim3(1024 / 32, 1024 / 32), dim3(32, 8), 0, stream>>>(w_out, woutT, 1024, 1024);
  cvt_T<<<dim3(T_TXT / 32, MTOT / 32), dim3(32, 8), 0, stream>>>(mask, maskT, MTOT, T_TXT);

  // 1) QKV projection (bf16 MFMA) with bf16 q/k/v scatter epilogue
  gemm_mfma<1><<<dim3(MTOT / 128, 3072 / 128), 256, 0, stream>>>(
      hbf, wqkvT, b_qkv, nullptr, qbuf, kbuf, vbuf, MTOT, 3072, 1024);

  // 2) attention (branch-free online softmax, 4 lanes/query, bf16 everywhere, f32 math)
  short* ctx = hbf;
  attn_text<<<(BN_TOT * T_TXT * 4) / 256, 256, 0, stream>>>(qbuf, kbuf, vbuf, (unsigned short*)maskT, ctx);
  attn_img0<<<(BN_TOT * 1024 * 4) / 256, 256, 0, stream>>>(qbuf, kbuf, vbuf, (unsigned short*)maskT, ctx);
  attn_img1<<<(BN_TOT * 4096 * 4) / 256, 256, 0, stream>>>(qbuf, kbuf, vbuf, (unsigned short*)maskT, ctx);

  // 3) output projection (bf16 MFMA)
  gemm_mfma<0><<<dim3(MTOT / 128, 1024 / 128), 256, 0, stream>>>(
      ctx, woutT, b_out, out, nullptr, nullptr, nullptr, MTOT, 1024, 1024);
}